// Round 1
// baseline (157.483 us; speedup 1.0000x reference)
//
#include <hip/hip_runtime.h>

// Problem constants (match reference)
#define BB 4096
#define DD 768
#define D4 192          // D / 4 (float4 lanes per row)
#define NCLS 1000
#define NST 4
#define MAXP 8
#define SHP 16

// Kernel 1: smean[st][d] = mean_p shared_protos[st][p][d]   (4 x 768 f32 out)
__global__ void smean_kernel(const float4* __restrict__ sp, float4* __restrict__ smean) {
    int idx = blockIdx.x * blockDim.x + threadIdx.x;   // 0 .. NST*D4-1
    if (idx >= NST * D4) return;
    int st = idx / D4;
    int d4 = idx - st * D4;
    const float4* p = sp + (size_t)(st * SHP) * D4 + d4;
    float4 acc = make_float4(0.f, 0.f, 0.f, 0.f);
    #pragma unroll
    for (int k = 0; k < SHP; ++k) {
        float4 v = p[(size_t)k * D4];
        acc.x += v.x; acc.y += v.y; acc.z += v.z; acc.w += v.w;
    }
    const float s = 1.0f / (float)SHP;
    acc.x *= s; acc.y *= s; acc.z *= s; acc.w *= s;
    smean[idx] = acc;
}

// Kernel 2: out[b][d] = feat[b][d] + 0.5*(cmean[b][d] + smean[stage[b]][d])
__global__ __launch_bounds__(256) void proto_pool_kernel(
    const float4* __restrict__ feat,
    const float4* __restrict__ cprotos,   // [NCLS, NST, MAXP, D4] float4
    const int*    __restrict__ cids,      // [B]
    const int*    __restrict__ stg,       // [B]
    const int*    __restrict__ cnts,      // [NCLS, NST]
    const float4* __restrict__ smean,     // [NST, D4] float4
    float4*       __restrict__ out)
{
    int idx = blockIdx.x * blockDim.x + threadIdx.x;   // 0 .. BB*D4-1
    int b  = idx / D4;                                  // row (wave-uniform: 192 = 3*64)
    int d4 = idx - b * D4;

    int cid = cids[b];
    int st  = stg[b];
    int cnt = cnts[cid * NST + st];

    const float4* cp = cprotos + ((size_t)(cid * NST + st) * MAXP) * D4 + d4;
    float4 acc = make_float4(0.f, 0.f, 0.f, 0.f);
    for (int p = 0; p < cnt; ++p) {
        float4 v = cp[(size_t)p * D4];
        acc.x += v.x; acc.y += v.y; acc.z += v.z; acc.w += v.w;
    }
    int cdiv = cnt > 0 ? cnt : 1;
    float inv = 1.0f / (float)cdiv;

    float4 sm = smean[st * D4 + d4];
    float4 f  = feat[idx];
    float4 o;
    o.x = f.x + 0.5f * (acc.x * inv + sm.x);
    o.y = f.y + 0.5f * (acc.y * inv + sm.y);
    o.z = f.z + 0.5f * (acc.z * inv + sm.z);
    o.w = f.w + 0.5f * (acc.w * inv + sm.w);
    out[idx] = o;
}

extern "C" void kernel_launch(void* const* d_in, const int* in_sizes, int n_in,
                              void* d_out, int out_size, void* d_ws, size_t ws_size,
                              hipStream_t stream) {
    const float4* feat    = (const float4*)d_in[0];   // [B, D] f32
    const float4* cprotos = (const float4*)d_in[1];   // [NCLS, NST, MAXP, D] f32
    const float4* sprotos = (const float4*)d_in[2];   // [NST, SHP, D] f32
    const int*    cids    = (const int*)d_in[3];      // [B] i32
    const int*    stg     = (const int*)d_in[4];      // [B] i32
    const int*    cnts    = (const int*)d_in[5];      // [NCLS, NST] i32

    float4* smean = (float4*)d_ws;                    // NST*D4 float4 = 12 KiB
    float4* out   = (float4*)d_out;

    // Kernel 1: per-stage shared mean (768 float4 outputs)
    {
        int total = NST * D4;
        int block = 256;
        int grid  = (total + block - 1) / block;      // 3 blocks
        smean_kernel<<<grid, block, 0, stream>>>(sprotos, smean);
    }

    // Kernel 2: fused gather/mean/add (786432 float4 outputs)
    {
        int total = BB * D4;
        int block = 256;
        int grid  = total / block;                    // 3072 blocks
        proto_pool_kernel<<<grid, block, 0, stream>>>(feat, cprotos, cids, stg, cnts,
                                                      smean, out);
    }
}

// Round 3
// 152.449 us; speedup vs baseline: 1.0330x; 1.0330x over previous
//
#include <hip/hip_runtime.h>

// Problem constants (match reference)
#define BB 4096
#define DD 768
#define D4 192          // D / 4 (float4 lanes per row)
#define NCLS 1000
#define NST 4
#define MAXP 8
#define SHP 16

// Native clang vector for nontemporal builtins (HIP_vector_type is rejected).
typedef float vfloat4 __attribute__((ext_vector_type(4)));

// Kernel 1: smean[st][d] = mean_p shared_protos[st][p][d]   (4 x 768 f32 out)
__global__ void smean_kernel(const float4* __restrict__ sp, float4* __restrict__ smean) {
    int idx = blockIdx.x * blockDim.x + threadIdx.x;   // 0 .. NST*D4-1
    if (idx >= NST * D4) return;
    int st = idx / D4;
    int d4 = idx - st * D4;
    const float4* p = sp + (size_t)(st * SHP) * D4 + d4;
    float4 acc = make_float4(0.f, 0.f, 0.f, 0.f);
    #pragma unroll
    for (int k = 0; k < SHP; ++k) {
        float4 v = p[(size_t)k * D4];
        acc.x += v.x; acc.y += v.y; acc.z += v.z; acc.w += v.w;
    }
    const float s = 1.0f / (float)SHP;
    acc.x *= s; acc.y *= s; acc.z *= s; acc.w *= s;
    smean[idx] = acc;
}

// Kernel 2: out[b][d] = feat[b][d] + 0.5*(cmean[b][d] + smean[stage[b]][d])
__global__ __launch_bounds__(256) void proto_pool_kernel(
    const float4* __restrict__ feat,
    const float4* __restrict__ cprotos,   // [NCLS, NST, MAXP, D4] float4
    const int*    __restrict__ cids,      // [B]
    const int*    __restrict__ stg,       // [B]
    const int*    __restrict__ cnts,      // [NCLS, NST]
    const float4* __restrict__ smean,     // [NST, D4] float4
    float4*       __restrict__ out)
{
    int idx = blockIdx.x * blockDim.x + threadIdx.x;   // 0 .. BB*D4-1
    int b  = idx / D4;                                  // row (wave-uniform: 192 = 3*64)
    int d4 = idx - b * D4;

    // b is wave-uniform: 192 float4 per row = exactly 3 waves. Scalarize the
    // index loads so cids/stg/cnts come through the scalar pipe (s_load).
    int bu = __builtin_amdgcn_readfirstlane(b);
    int cid = cids[bu];
    int st  = stg[bu];
    int cnt = cnts[cid * NST + st];

    // Streamed once — don't pollute L2 (keep it for the proto gather).
    vfloat4 f  = __builtin_nontemporal_load((const vfloat4*)feat + idx);
    float4 sm = smean[st * D4 + d4];

    // Fully-unrolled predicated gather: up to 8 independent loads in flight
    // (cnt is wave-uniform, so the skipped branches cost nothing).
    const float4* cp = cprotos + ((size_t)(cid * NST + st) * MAXP) * D4 + d4;
    float4 v[MAXP];
    #pragma unroll
    for (int p = 0; p < MAXP; ++p) {
        if (p < cnt) v[p] = cp[(size_t)p * D4];
    }
    float4 acc = make_float4(0.f, 0.f, 0.f, 0.f);
    #pragma unroll
    for (int p = 0; p < MAXP; ++p) {
        if (p < cnt) {
            acc.x += v[p].x; acc.y += v[p].y; acc.z += v[p].z; acc.w += v[p].w;
        }
    }
    int cdiv = cnt > 0 ? cnt : 1;
    float inv = 1.0f / (float)cdiv;

    vfloat4 o;
    o.x = f.x + 0.5f * (acc.x * inv + sm.x);
    o.y = f.y + 0.5f * (acc.y * inv + sm.y);
    o.z = f.z + 0.5f * (acc.z * inv + sm.z);
    o.w = f.w + 0.5f * (acc.w * inv + sm.w);
    __builtin_nontemporal_store(o, (vfloat4*)out + idx);
}

extern "C" void kernel_launch(void* const* d_in, const int* in_sizes, int n_in,
                              void* d_out, int out_size, void* d_ws, size_t ws_size,
                              hipStream_t stream) {
    const float4* feat    = (const float4*)d_in[0];   // [B, D] f32
    const float4* cprotos = (const float4*)d_in[1];   // [NCLS, NST, MAXP, D] f32
    const float4* sprotos = (const float4*)d_in[2];   // [NST, SHP, D] f32
    const int*    cids    = (const int*)d_in[3];      // [B] i32
    const int*    stg     = (const int*)d_in[4];      // [B] i32
    const int*    cnts    = (const int*)d_in[5];      // [NCLS, NST] i32

    float4* smean = (float4*)d_ws;                    // NST*D4 float4 = 12 KiB
    float4* out   = (float4*)d_out;

    // Kernel 1: per-stage shared mean (768 float4 outputs)
    {
        int total = NST * D4;
        int block = 256;
        int grid  = (total + block - 1) / block;      // 3 blocks
        smean_kernel<<<grid, block, 0, stream>>>(sprotos, smean);
    }

    // Kernel 2: fused gather/mean/add (786432 float4 outputs)
    {
        int total = BB * D4;
        int block = 256;
        int grid  = total / block;                    // 3072 blocks
        proto_pool_kernel<<<grid, block, 0, stream>>>(feat, cprotos, cids, stg, cnts,
                                                      smean, out);
    }
}